// Round 7
// baseline (291.313 us; speedup 1.0000x reference)
//
#include <hip/hip_runtime.h>
#include <hip/hip_bf16.h>
#include <stdint.h>

#define NN 32768
#define KK 1024
#define DD 256
#define BM 16
#define CHUNK 128
#define NCHUNK 8
#define NTHR 512

// LDS: Xs 8KB + scratch 2KB (PRE); !PRE adds 64KB Ps
#define LXS 0            // 16 rows * 512B bf16, 16B-granule XOR-swizzled
#define SC_MAXP 8192     // [16 rows][8 waves] {f32 max, i32 argmax} = 1024 B
#define SC_ZP   9216     // [16][8] f32 sumexp partials = 512 B
#define SC_LZ   9728     // [16] f32 logZ
#define SC_MI   9792     // [16] i32 argmax
#define LSCR_END 10240
#define LPS 10240        // (!PRE only) 128 protos * 512B

// ws layout (floats): [0,1024) np2 | [1024,2048) colsum_y | [2048,3072) colsum_lp
// | bytes [12288, 12288+524288) Pbf16 row-major (fast path)

typedef __attribute__((ext_vector_type(8))) short bf16x8;
typedef __attribute__((ext_vector_type(4))) float f32x4;

__device__ __forceinline__ uint32_t pkbf2(float a, float b) {  // RNE f32->bf16 pack
    uint32_t ua = __builtin_bit_cast(uint32_t, a);
    uint32_t ub = __builtin_bit_cast(uint32_t, b);
    ua = (ua + 0x7fffu + ((ua >> 16) & 1u)) >> 16;
    ub = (ub + 0x7fffu + ((ub >> 16) & 1u)) >> 16;
    return ua | (ub << 16);
}
__device__ __forceinline__ float ubf(uint32_t h) {  // bf16 bits -> f32 (exact)
    return __builtin_bit_cast(float, h << 16);
}

__global__ void vq_init(const float* __restrict__ protos, float* __restrict__ ws) {
    int k = blockIdx.x * 256 + threadIdx.x;   // grid 4 x 256 -> 1024 protos
    const float4* p4 = reinterpret_cast<const float4*>(protos + (size_t)k * DD);
    float s = 0.f;
#pragma unroll 8
    for (int j = 0; j < DD / 4; ++j) {
        float4 v = p4[j];
        s = fmaf(v.x, v.x, s); s = fmaf(v.y, v.y, s);
        s = fmaf(v.z, v.z, s); s = fmaf(v.w, v.w, s);
    }
    ws[k] = s;
    ws[KK + k] = 0.f;
    ws[2 * KK + k] = 0.f;
}

__global__ void vq_cvt(const float* __restrict__ protos, uint32_t* __restrict__ pb) {
    int idx = blockIdx.x * 256 + threadIdx.x;  // 0..32767, 8 floats each
    const float4* s = reinterpret_cast<const float4*>(protos + (size_t)idx * 8);
    float4 a = s[0], b = s[1];
    uint4 v;
    v.x = pkbf2(a.x, a.y); v.y = pkbf2(a.z, a.w);
    v.z = pkbf2(b.x, b.y); v.w = pkbf2(b.z, b.w);
    reinterpret_cast<uint4*>(pb)[idx] = v;
}

template<bool PRE>
__global__ __launch_bounds__(NTHR) void vq_mainT(const float* __restrict__ latents,
                                                 const float* __restrict__ protos,
                                                 const float* __restrict__ gumbel,
                                                 float* __restrict__ ws,
                                                 float* __restrict__ out) {
    __shared__ __align__(16) unsigned char sm[PRE ? LSCR_END : (LSCR_END + 65536)];
    const int t = threadIdx.x;
    const int lane = t & 63;
    const int w = t >> 6;                 // wave 0..7
    const int n0 = blockIdx.x * BM;
    const int l15 = lane & 15;
    const int l4 = lane >> 4;
    const float* np2 = ws;
    float* colsum_y = ws + KK;
    float* colsum_lp = ws + 2 * KK;
    const uint4* pb = reinterpret_cast<const uint4*>(ws + 3 * KK);

    // ---- stage X: 16 rows x 256 f32 -> bf16 LDS (swizzled), 1 granule/thread ----
    {
        int row = t >> 5, g = t & 31;
        const float4* src = reinterpret_cast<const float4*>(
            latents + (size_t)(n0 + row) * DD + g * 8);
        float4 a = src[0], b = src[1];
        uint4 v; v.x = pkbf2(a.x, a.y); v.y = pkbf2(a.z, a.w);
        v.z = pkbf2(b.x, b.y); v.w = pkbf2(b.z, b.w);
        *reinterpret_cast<uint4*>(sm + LXS + row * 512 + ((g ^ (row & 7)) << 4)) = v;
    }
    if (PRE) __syncthreads();

    const int cwbase = w * 16 + l4 * 4;   // per-thread column base within chunk
    const int pr = w * 16 + l15;          // proto row (local) for A-frag
    uint32_t Sp[16];                      // packed bf16 S, 2 per chunk
    float z = 0.f, m = -3.4e38f; int mi = 0;

#pragma unroll
    for (int c = 0; c < NCHUNK; ++c) {
        if (!PRE) {
            __syncthreads();
#pragma unroll
            for (int i = 0; i < 8; ++i) {
                int G = t + NTHR * i;
                int p = G >> 5, g = G & 31;
                const float4* src = reinterpret_cast<const float4*>(
                    protos + (size_t)(c * CHUNK + p) * DD + g * 8);
                float4 a = src[0], b = src[1];
                uint4 v; v.x = pkbf2(a.x, a.y); v.y = pkbf2(a.z, a.w);
                v.z = pkbf2(b.x, b.y); v.w = pkbf2(b.z, b.w);
                *reinterpret_cast<uint4*>(sm + LPS + p * 512 + ((g ^ (p & 7)) << 4)) = v;
            }
            __syncthreads();
        }
        const int pg0 = c * CHUNK + cwbase;
        float4 q4 = *reinterpret_cast<const float4*>(np2 + pg0);
        float4 g4 = *reinterpret_cast<const float4*>(gumbel + (size_t)(n0 + l15) * KK + pg0);

        f32x4 acc = {0.f, 0.f, 0.f, 0.f};
        if (PRE) {
            const uint4* afp = pb + (size_t)(c * CHUNK + pr) * 32;  // 32 granules/proto
#pragma unroll
            for (int ks = 0; ks < 8; ++ks) {
                int gi = ks * 4 + l4;
                bf16x8 af = __builtin_bit_cast(bf16x8, afp[gi]);
                bf16x8 b0 = *reinterpret_cast<bf16x8*>(
                    sm + LXS + l15 * 512 + ((gi ^ (l15 & 7)) << 4));
                acc = __builtin_amdgcn_mfma_f32_16x16x32_bf16(af, b0, acc, 0, 0, 0);
            }
        } else {
#pragma unroll
            for (int ks = 0; ks < 8; ++ks) {
                int gi = ks * 4 + l4;
                bf16x8 af = *reinterpret_cast<bf16x8*>(
                    sm + LPS + pr * 512 + ((gi ^ (pr & 7)) << 4));
                bf16x8 b0 = *reinterpret_cast<bf16x8*>(
                    sm + LXS + l15 * 512 + ((gi ^ (l15 & 7)) << 4));
                acc = __builtin_amdgcn_mfma_f32_16x16x32_bf16(af, b0, acc, 0, 0, 0);
            }
        }
        // ---- fused epilogue: S, online sumexp (no max-sub: S<=~17, f32-safe), argmax ----
        float s0 = fmaf(2.f, acc.x, -q4.x) + g4.x;
        float s1 = fmaf(2.f, acc.y, -q4.y) + g4.y;
        float s2 = fmaf(2.f, acc.z, -q4.z) + g4.z;
        float s3 = fmaf(2.f, acc.w, -q4.w) + g4.w;
        z += __expf(s0) + __expf(s1) + __expf(s2) + __expf(s3);
        if (s0 > m) { m = s0; mi = pg0; }
        if (s1 > m) { m = s1; mi = pg0 + 1; }
        if (s2 > m) { m = s2; mi = pg0 + 2; }
        if (s3 > m) { m = s3; mi = pg0 + 3; }
        Sp[c * 2]     = pkbf2(s0, s1);
        Sp[c * 2 + 1] = pkbf2(s2, s3);
    }

    // ---- Phase B: reduce z / argmax over l4 (lane bits 4,5), then across waves ----
#pragma unroll
    for (int off = 16; off <= 32; off <<= 1) {
        float om = __shfl_xor(m, off); int oi = __shfl_xor(mi, off);
        if (om > m || (om == m && oi < mi)) { m = om; mi = oi; }
        z += __shfl_xor(z, off);
    }
    if (lane < 16) {
        *reinterpret_cast<float*>(sm + SC_MAXP + (l15 * 8 + w) * 8) = m;
        *reinterpret_cast<int*>(sm + SC_MAXP + (l15 * 8 + w) * 8 + 4) = mi;
        *reinterpret_cast<float*>(sm + SC_ZP + (l15 * 8 + w) * 4) = z;
    }
    __syncthreads();
    if (t < 16) {
        float mm = -3.4e38f; int mmi = 0; float Z = 0.f;
#pragma unroll
        for (int j = 0; j < 8; ++j) {
            float om = *reinterpret_cast<float*>(sm + SC_MAXP + (t * 8 + j) * 8);
            int oi = *reinterpret_cast<int*>(sm + SC_MAXP + (t * 8 + j) * 8 + 4);
            if (om > mm || (om == mm && oi < mmi)) { mm = om; mmi = oi; }
            Z += *reinterpret_cast<float*>(sm + SC_ZP + (t * 8 + j) * 4);
        }
        *reinterpret_cast<float*>(sm + SC_LZ + t * 4) = __logf(Z);
        *reinterpret_cast<int*>(sm + SC_MI + t * 4) = mmi;
    }
    __syncthreads();

    // ---- Phase C1: column sums (reduce 16 rows across l15 lanes, atomics) ----
    {
        float lz = *reinterpret_cast<float*>(sm + SC_LZ + l15 * 4);
#pragma unroll
        for (int c = 0; c < NCHUNK; ++c) {
            float a0 = ubf(Sp[c*2] & 0xffffu) - lz, a1 = ubf(Sp[c*2] >> 16) - lz;
            float a2 = ubf(Sp[c*2+1] & 0xffffu) - lz, a3 = ubf(Sp[c*2+1] >> 16) - lz;
            float y0 = __expf(a0), y1 = __expf(a1), y2 = __expf(a2), y3 = __expf(a3);
#pragma unroll
            for (int off = 1; off < 16; off <<= 1) {
                y0 += __shfl_xor(y0, off); y1 += __shfl_xor(y1, off);
                y2 += __shfl_xor(y2, off); y3 += __shfl_xor(y3, off);
                a0 += __shfl_xor(a0, off); a1 += __shfl_xor(a1, off);
                a2 += __shfl_xor(a2, off); a3 += __shfl_xor(a3, off);
            }
            if (l15 == 0) {
                int cb = c * CHUNK + cwbase;
                atomicAdd(&colsum_y[cb],     y0); atomicAdd(&colsum_y[cb + 1], y1);
                atomicAdd(&colsum_y[cb + 2], y2); atomicAdd(&colsum_y[cb + 3], y3);
                atomicAdd(&colsum_lp[cb],     a0); atomicAdd(&colsum_lp[cb + 1], a1);
                atomicAdd(&colsum_lp[cb + 2], a2); atomicAdd(&colsum_lp[cb + 3], a3);
            }
        }
    }

    // ---- Phase C2: quantized = protos[argmax] (f32 gather), 32 thr/row ----
    {
        int row = t >> 5, v = t & 31;
        int idx = *reinterpret_cast<int*>(sm + SC_MI + row * 4);
        const float4* src = reinterpret_cast<const float4*>(protos + (size_t)idx * DD + v * 8);
        float4* dst = reinterpret_cast<float4*>(out + (size_t)(n0 + row) * DD + v * 8);
        dst[0] = src[0];
        dst[1] = src[1];
    }
}

__global__ void vq_final(const float* __restrict__ ws,
                         float* __restrict__ out, int out_size) {
    __shared__ float part[4];
    int t = threadIdx.x;  // 1 block x 256
    const float invN = 1.0f / (float)NN;
    float a = 0.f;
    for (int j = 0; j < 4; ++j) {
        int k = t + j * 256;
        float prior = fmaf(ws[KK + k], invN, 1e-6f);
        float Lk = ws[2 * KK + k] * invN;
        a += prior * (1.001f * __logf(prior) - Lk);
    }
#pragma unroll
    for (int off = 32; off >= 1; off >>= 1) a += __shfl_xor(a, off);
    if ((t & 63) == 0) part[t >> 6] = a;
    __syncthreads();
    if (t == 0) {
        out[out_size - 1] = part[0] + part[1] + part[2] + part[3];
    }
}

extern "C" void kernel_launch(void* const* d_in, const int* in_sizes, int n_in,
                              void* d_out, int out_size, void* d_ws, size_t ws_size,
                              hipStream_t stream) {
    (void)in_sizes; (void)n_in;
    const float* latents = (const float*)d_in[0];
    const float* protos  = (const float*)d_in[1];
    const float* gumbel  = (const float*)d_in[2];
    float* out           = (float*)d_out;
    float* ws            = (float*)d_ws;

    bool pre = ws_size >= (size_t)(3 * KK * 4 + KK * DD * 2);

    vq_init<<<dim3(4), dim3(256), 0, stream>>>(protos, ws);
    if (pre) {
        vq_cvt<<<dim3(KK * DD / 2048), dim3(256), 0, stream>>>(
            protos, (uint32_t*)(ws + 3 * KK));
        vq_mainT<true><<<dim3(NN / BM), dim3(NTHR), 0, stream>>>(
            latents, protos, gumbel, ws, out);
    } else {
        vq_mainT<false><<<dim3(NN / BM), dim3(NTHR), 0, stream>>>(
            latents, protos, gumbel, ws, out);
    }
    vq_final<<<dim3(1), dim3(256), 0, stream>>>(ws, out, out_size);
}

// Round 8
// 222.956 us; speedup vs baseline: 1.3066x; 1.3066x over previous
//
#include <hip/hip_runtime.h>
#include <hip/hip_bf16.h>
#include <stdint.h>

#define NN 32768
#define KK 1024
#define DD 256
#define BM 32
#define CHUNK 128
#define NCHUNK (KK / CHUNK)   // 8
#define NTHR 512

// LDS byte offsets (total 147712 B): Xs 16KB | Ps 64KB | Ss 64KB | stats
#define LXS 0                   // 32 rows * 512B bf16, 16B-granule XOR-swizzled
#define LPS 16384               // 128 protos * 512B bf16, swizzled
#define LSS (LPS + 65536)       // 32 rows * 2048B bf16, 8B-granule swizzled
#define LRM (LSS + 65536)       // row logZ f32[32]
#define LRI (LRM + 128)         // row argmax i32[32]
#define LTOT (LRI + 128)

// ws layout (floats): [0,1024) np2 | [1024,2048) colsum_y | [2048,3072) colsum_lp
// | bytes [12288, 12288+524288) Pbf16 (fast path)

typedef __attribute__((ext_vector_type(8))) short bf16x8;
typedef __attribute__((ext_vector_type(4))) float f32x4;

__device__ __forceinline__ uint32_t pkbf2(float a, float b) {  // RNE f32->bf16 pack
    uint32_t ua = __builtin_bit_cast(uint32_t, a);
    uint32_t ub = __builtin_bit_cast(uint32_t, b);
    ua = (ua + 0x7fffu + ((ua >> 16) & 1u)) >> 16;
    ub = (ub + 0x7fffu + ((ub >> 16) & 1u)) >> 16;
    return ua | (ub << 16);
}
__device__ __forceinline__ float ubf(uint32_t h) {  // bf16 bits -> f32 (exact)
    return __builtin_bit_cast(float, h << 16);
}

__global__ void vq_init(const float* __restrict__ protos, float* __restrict__ ws) {
    int k = blockIdx.x * 256 + threadIdx.x;   // grid 4 x 256
    const float4* p4 = reinterpret_cast<const float4*>(protos + (size_t)k * DD);
    float s = 0.f;
#pragma unroll 8
    for (int j = 0; j < DD / 4; ++j) {
        float4 v = p4[j];
        s = fmaf(v.x, v.x, s); s = fmaf(v.y, v.y, s);
        s = fmaf(v.z, v.z, s); s = fmaf(v.w, v.w, s);
    }
    ws[k] = s;
    ws[KK + k] = 0.f;
    ws[2 * KK + k] = 0.f;
}

__global__ void vq_cvt(const float* __restrict__ protos, uint32_t* __restrict__ pb) {
    int idx = blockIdx.x * 256 + threadIdx.x;  // 0..32767, 8 floats each
    const float4* s = reinterpret_cast<const float4*>(protos + (size_t)idx * 8);
    float4 a = s[0], b = s[1];
    uint4 v;
    v.x = pkbf2(a.x, a.y); v.y = pkbf2(a.z, a.w);
    v.z = pkbf2(b.x, b.y); v.w = pkbf2(b.z, b.w);
    reinterpret_cast<uint4*>(pb)[idx] = v;
}

template<bool PRE>
__global__ __launch_bounds__(NTHR) void vq_mainT(const float* __restrict__ latents,
                                                 const float* __restrict__ protos,
                                                 const float* __restrict__ gumbel,
                                                 float* __restrict__ ws,
                                                 float* __restrict__ out) {
    __shared__ __align__(16) unsigned char sm[LTOT];
    const int t = threadIdx.x;
    const int lane = t & 63;
    const int w = t >> 6;                 // wave 0..7
    const int n0 = blockIdx.x * BM;
    const int l15 = lane & 15;
    const int l4 = lane >> 4;
    const float* np2 = ws;
    float* colsum_y = ws + KK;
    float* colsum_lp = ws + 2 * KK;
    const uint4* pb = reinterpret_cast<const uint4*>(ws + 3 * KK);

    // ---- stage X: 32 rows x 256 f32 -> bf16 LDS (swizzled) ----
    {
        int row = t >> 4;
        int g0 = (t & 15) * 2;
#pragma unroll
        for (int j = 0; j < 2; ++j) {
            int g = g0 + j;
            const float4* src = reinterpret_cast<const float4*>(
                latents + (size_t)(n0 + row) * DD + g * 8);
            float4 a = src[0], b = src[1];
            uint4 v; v.x = pkbf2(a.x, a.y); v.y = pkbf2(a.z, a.w);
            v.z = pkbf2(b.x, b.y); v.w = pkbf2(b.z, b.w);
            *reinterpret_cast<uint4*>(sm + LXS + row * 512 + ((g ^ (row & 7)) << 4)) = v;
        }
    }

    const int pr = w * 16 + l15;          // proto row (local) for A-frag
    const int cwbase = w * 16 + l4 * 4;   // per-thread column base within chunk
    const int pfp = t >> 5;               // this thread's staging proto row
    const int pfg = t & 31;               // and 16B-granule within row

    // T14 async-stage: prefetch chunk 0 into registers
    uint4 pf[8];
    if (PRE) {
#pragma unroll
        for (int i = 0; i < 8; ++i)
            pf[i] = pb[(size_t)(pfp + 16 * i) * 32 + pfg];
    }

    for (int c = 0; c < NCHUNK; ++c) {
        __syncthreads();                  // prev chunk Ps reads done / Xs visible
        if (PRE) {
            // write prefetched regs -> Ps LDS (swizzled)
#pragma unroll
            for (int i = 0; i < 8; ++i) {
                int p = pfp + 16 * i;
                *reinterpret_cast<uint4*>(sm + LPS + p * 512 + ((pfg ^ (p & 7)) << 4)) = pf[i];
            }
            // issue next chunk's loads: latency hides under this chunk's MFMA
            if (c + 1 < NCHUNK) {
#pragma unroll
                for (int i = 0; i < 8; ++i)
                    pf[i] = pb[(size_t)((c + 1) * CHUNK + pfp + 16 * i) * 32 + pfg];
            }
        } else {
#pragma unroll
            for (int i = 0; i < 8; ++i) {
                int G = t + NTHR * i;
                int p = G >> 5, g = G & 31;
                const float4* src = reinterpret_cast<const float4*>(
                    protos + (size_t)(c * CHUNK + p) * DD + g * 8);
                float4 a = src[0], b = src[1];
                uint4 v; v.x = pkbf2(a.x, a.y); v.y = pkbf2(a.z, a.w);
                v.z = pkbf2(b.x, b.y); v.w = pkbf2(b.z, b.w);
                *reinterpret_cast<uint4*>(sm + LPS + p * 512 + ((g ^ (p & 7)) << 4)) = v;
            }
        }
        __syncthreads();

        // prefetch epilogue operands (hide HBM latency under MFMA)
        const int pg0 = c * CHUNK + cwbase;
        float4 q4 = *reinterpret_cast<const float4*>(np2 + pg0);
        float4 g40 = *reinterpret_cast<const float4*>(gumbel + (size_t)(n0 + l15) * KK + pg0);
        float4 g41 = *reinterpret_cast<const float4*>(gumbel + (size_t)(n0 + 16 + l15) * KK + pg0);

        f32x4 acc0 = {0.f, 0.f, 0.f, 0.f}, acc1 = {0.f, 0.f, 0.f, 0.f};
#pragma unroll
        for (int ks = 0; ks < 8; ++ks) {
            int gi = ks * 4 + l4;
            bf16x8 af = *reinterpret_cast<bf16x8*>(sm + LPS + pr * 512 + ((gi ^ (pr & 7)) << 4));
            bf16x8 b0 = *reinterpret_cast<bf16x8*>(sm + LXS + l15 * 512 + ((gi ^ (l15 & 7)) << 4));
            bf16x8 b1 = *reinterpret_cast<bf16x8*>(sm + LXS + (16 + l15) * 512 + ((gi ^ ((16 + l15) & 7)) << 4));
            acc0 = __builtin_amdgcn_mfma_f32_16x16x32_bf16(af, b0, acc0, 0, 0, 0);
            acc1 = __builtin_amdgcn_mfma_f32_16x16x32_bf16(af, b1, acc1, 0, 0, 0);
        }
        // ---- epilogue: S = 2*acc - np2 + gumbel -> bf16 Ss (swizzled b64 writes) ----
        const int Gs = pg0 >> 2;          // 8B-granule index within row
        {
            int xrow = l15;
            uint2 pk;
            pk.x = pkbf2(fmaf(2.f, acc0.x, -q4.x) + g40.x, fmaf(2.f, acc0.y, -q4.y) + g40.y);
            pk.y = pkbf2(fmaf(2.f, acc0.z, -q4.z) + g40.z, fmaf(2.f, acc0.w, -q4.w) + g40.w);
            *reinterpret_cast<uint2*>(sm + LSS + xrow * 2048 + ((Gs ^ ((xrow & 7) << 1)) << 3)) = pk;
        }
        {
            int xrow = 16 + l15;
            uint2 pk;
            pk.x = pkbf2(fmaf(2.f, acc1.x, -q4.x) + g41.x, fmaf(2.f, acc1.y, -q4.y) + g41.y);
            pk.y = pkbf2(fmaf(2.f, acc1.z, -q4.z) + g41.z, fmaf(2.f, acc1.w, -q4.w) + g41.w);
            *reinterpret_cast<uint2*>(sm + LSS + xrow * 2048 + ((Gs ^ ((xrow & 7) << 1)) << 3)) = pk;
        }
    }
    __syncthreads();

    // ---- Phase B: per-row max/argmax/logZ (16 threads per row) ----
    {
        int row = t >> 4, v = t & 15;
        int sw = (row & 7) << 1;
        uint2 d[16];
#pragma unroll
        for (int j = 0; j < 16; ++j) {
            int G = v + 16 * j;
            d[j] = *reinterpret_cast<uint2*>(sm + LSS + row * 2048 + ((G ^ sw) << 3));
        }
        float m = -3.4e38f; int mi = 0;
#pragma unroll
        for (int j = 0; j < 16; ++j) {
            int c0 = (v + 16 * j) * 4;
            float f0 = ubf(d[j].x & 0xffffu), f1 = ubf(d[j].x >> 16);
            float f2 = ubf(d[j].y & 0xffffu), f3 = ubf(d[j].y >> 16);
            if (f0 > m) { m = f0; mi = c0; }
            if (f1 > m) { m = f1; mi = c0 + 1; }
            if (f2 > m) { m = f2; mi = c0 + 2; }
            if (f3 > m) { m = f3; mi = c0 + 3; }
        }
#pragma unroll
        for (int off = 1; off < 16; off <<= 1) {
            float om = __shfl_xor(m, off);
            int oi = __shfl_xor(mi, off);
            if (om > m || (om == m && oi < mi)) { m = om; mi = oi; }
        }
        float se = 0.f;
#pragma unroll
        for (int j = 0; j < 16; ++j) {
            se += __expf(ubf(d[j].x & 0xffffu) - m);
            se += __expf(ubf(d[j].x >> 16) - m);
            se += __expf(ubf(d[j].y & 0xffffu) - m);
            se += __expf(ubf(d[j].y >> 16) - m);
        }
#pragma unroll
        for (int off = 1; off < 16; off <<= 1) se += __shfl_xor(se, off);
        if (v == 0) {
            *reinterpret_cast<float*>(sm + LRM + row * 4) = m + __logf(se);
            *reinterpret_cast<int*>(sm + LRI + row * 4) = mi;
        }
    }
    __syncthreads();

    // ---- Phase C1: column partial sums -> global atomics ----
#pragma unroll
    for (int h = 0; h < 2; ++h) {
        int col = t + h * NTHR;
        int G = col >> 2;
        int e2 = (col & 3) << 1;
        float sy = 0.f, slp = 0.f;
#pragma unroll 8
        for (int r = 0; r < BM; ++r) {
            uint32_t hv = *reinterpret_cast<uint16_t*>(
                sm + LSS + r * 2048 + ((G ^ ((r & 7) << 1)) << 3) + e2);
            float lz = *reinterpret_cast<float*>(sm + LRM + r * 4);
            float lp = ubf(hv) - lz;
            slp += lp;
            sy += __expf(lp);
        }
        atomicAdd(&colsum_y[col], sy);
        atomicAdd(&colsum_lp[col], slp);
    }

    // ---- Phase C2: quantized = protos[argmax] (f32 gather) ----
    {
        int row = t >> 4, v = t & 15;
        int idx = *reinterpret_cast<int*>(sm + LRI + row * 4);
        const float4* src = reinterpret_cast<const float4*>(protos + (size_t)idx * DD + v * 16);
        float4* dst = reinterpret_cast<float4*>(out + (size_t)(n0 + row) * DD + v * 16);
#pragma unroll
        for (int j = 0; j < 4; ++j) dst[j] = src[j];
    }
}

__global__ void vq_final(const float* __restrict__ ws,
                         float* __restrict__ out, int out_size) {
    __shared__ float part[4];
    int t = threadIdx.x;  // 1 block x 256
    const float invN = 1.0f / (float)NN;
    float a = 0.f;
    for (int j = 0; j < 4; ++j) {
        int k = t + j * 256;
        float prior = fmaf(ws[KK + k], invN, 1e-6f);
        float Lk = ws[2 * KK + k] * invN;
        a += prior * (1.001f * __logf(prior) - Lk);
    }
#pragma unroll
    for (int off = 32; off >= 1; off >>= 1) a += __shfl_xor(a, off);
    if ((t & 63) == 0) part[t >> 6] = a;
    __syncthreads();
    if (t == 0) {
        out[out_size - 1] = part[0] + part[1] + part[2] + part[3];
    }
}

extern "C" void kernel_launch(void* const* d_in, const int* in_sizes, int n_in,
                              void* d_out, int out_size, void* d_ws, size_t ws_size,
                              hipStream_t stream) {
    (void)in_sizes; (void)n_in;
    const float* latents = (const float*)d_in[0];
    const float* protos  = (const float*)d_in[1];
    const float* gumbel  = (const float*)d_in[2];
    float* out           = (float*)d_out;
    float* ws            = (float*)d_ws;

    bool pre = ws_size >= (size_t)(3 * KK * 4 + KK * DD * 2);

    vq_init<<<dim3(4), dim3(256), 0, stream>>>(protos, ws);
    if (pre) {
        vq_cvt<<<dim3(KK * DD / 2048), dim3(256), 0, stream>>>(
            protos, (uint32_t*)(ws + 3 * KK));
        vq_mainT<true><<<dim3(NN / BM), dim3(NTHR), 0, stream>>>(
            latents, protos, gumbel, ws, out);
    } else {
        vq_mainT<false><<<dim3(NN / BM), dim3(NTHR), 0, stream>>>(
            latents, protos, gumbel, ws, out);
    }
    vq_final<<<dim3(1), dim3(256), 0, stream>>>(ws, out, out_size);
}

// Round 9
// 163.958 us; speedup vs baseline: 1.7768x; 1.3598x over previous
//
#include <hip/hip_runtime.h>
#include <hip/hip_bf16.h>
#include <stdint.h>

#define NN 32768
#define KK 1024
#define DD 256
#define BM 16
#define CHUNK 128
#define NCHUNK (KK / CHUNK)   // 8
#define NTHR 512

// LDS (PRE path): Xs 8KB | Ss 32KB | stats ~0.5KB  => ~41KB -> 2-3 blocks/CU
#define LXS 0                   // 16 rows * 512B bf16, 16B-granule XOR-swizzled
#define LSS 8192                // 16 rows * 2048B bf16, 8B-granule XOR-swizzled
#define LRM (LSS + 32768)       // row logZ f32[16]
#define LRI (LRM + 64)          // row argmax i32[16]
#define LEND (LRI + 64)         // 41088
#define LPS 41216               // (!PRE only) 128 protos * 512B swizzled
#define LTOT_PRE  41216
#define LTOT_NPRE (41216 + 65536)

// ws layout (floats): [0,1024) np2 | [1024,2048) colsum_y | [2048,3072) colsum_lp
// | bytes [12288, 12288+524288) Pbf16 row-major (fast path)

typedef __attribute__((ext_vector_type(8))) short bf16x8;
typedef __attribute__((ext_vector_type(4))) float f32x4;

__device__ __forceinline__ uint32_t pkbf2(float a, float b) {  // RNE f32->bf16 pack
    uint32_t ua = __builtin_bit_cast(uint32_t, a);
    uint32_t ub = __builtin_bit_cast(uint32_t, b);
    ua = (ua + 0x7fffu + ((ua >> 16) & 1u)) >> 16;
    ub = (ub + 0x7fffu + ((ub >> 16) & 1u)) >> 16;
    return ua | (ub << 16);
}
__device__ __forceinline__ float ubf(uint32_t h) {  // bf16 bits -> f32 (exact)
    return __builtin_bit_cast(float, h << 16);
}

__global__ void vq_init(const float* __restrict__ protos, float* __restrict__ ws) {
    int k = blockIdx.x * 256 + threadIdx.x;   // grid 4 x 256
    const float4* p4 = reinterpret_cast<const float4*>(protos + (size_t)k * DD);
    float s = 0.f;
#pragma unroll 8
    for (int j = 0; j < DD / 4; ++j) {
        float4 v = p4[j];
        s = fmaf(v.x, v.x, s); s = fmaf(v.y, v.y, s);
        s = fmaf(v.z, v.z, s); s = fmaf(v.w, v.w, s);
    }
    ws[k] = s;
    ws[KK + k] = 0.f;
    ws[2 * KK + k] = 0.f;
}

__global__ void vq_cvt(const float* __restrict__ protos, uint32_t* __restrict__ pb) {
    int idx = blockIdx.x * 256 + threadIdx.x;  // 0..32767, 8 floats each
    const float4* s = reinterpret_cast<const float4*>(protos + (size_t)idx * 8);
    float4 a = s[0], b = s[1];
    uint4 v;
    v.x = pkbf2(a.x, a.y); v.y = pkbf2(a.z, a.w);
    v.z = pkbf2(b.x, b.y); v.w = pkbf2(b.z, b.w);
    reinterpret_cast<uint4*>(pb)[idx] = v;
}

template<bool PRE>
__global__ __launch_bounds__(NTHR) void vq_mainT(const float* __restrict__ latents,
                                                 const float* __restrict__ protos,
                                                 const float* __restrict__ gumbel,
                                                 float* __restrict__ ws,
                                                 float* __restrict__ out) {
    __shared__ __align__(16) unsigned char sm[PRE ? LTOT_PRE : LTOT_NPRE];
    const int t = threadIdx.x;
    const int lane = t & 63;
    const int w = t >> 6;                 // wave 0..7
    const int n0 = blockIdx.x * BM;
    const int l15 = lane & 15;
    const int l4 = lane >> 4;
    const float* np2 = ws;
    float* colsum_y = ws + KK;
    float* colsum_lp = ws + 2 * KK;
    const uint4* pb = reinterpret_cast<const uint4*>(ws + 3 * KK);

    // ---- stage X: 16 rows x 256 f32 -> bf16 LDS (swizzled), 1 granule/thread ----
    {
        int row = t >> 5, g = t & 31;
        const float4* src = reinterpret_cast<const float4*>(
            latents + (size_t)(n0 + row) * DD + g * 8);
        float4 a = src[0], b = src[1];
        uint4 v; v.x = pkbf2(a.x, a.y); v.y = pkbf2(a.z, a.w);
        v.z = pkbf2(b.x, b.y); v.w = pkbf2(b.z, b.w);
        *reinterpret_cast<uint4*>(sm + LXS + row * 512 + ((g ^ (row & 7)) << 4)) = v;
    }
    __syncthreads();

    const int pr = w * 16 + l15;          // proto row (local) for A-frag
    const int cwbase = w * 16 + l4 * 4;   // per-thread column base within chunk

    for (int c = 0; c < NCHUNK; ++c) {
        if (!PRE) {
            __syncthreads();
#pragma unroll
            for (int i = 0; i < 8; ++i) {
                int G = t + NTHR * i;
                int p = G >> 5, g = G & 31;
                const float4* src = reinterpret_cast<const float4*>(
                    protos + (size_t)(c * CHUNK + p) * DD + g * 8);
                float4 a = src[0], b = src[1];
                uint4 v; v.x = pkbf2(a.x, a.y); v.y = pkbf2(a.z, a.w);
                v.z = pkbf2(b.x, b.y); v.w = pkbf2(b.z, b.w);
                *reinterpret_cast<uint4*>(sm + LPS + p * 512 + ((g ^ (p & 7)) << 4)) = v;
            }
            __syncthreads();
        }
        const int pg0 = c * CHUNK + cwbase;
        float4 q4 = *reinterpret_cast<const float4*>(np2 + pg0);
        float4 g4 = *reinterpret_cast<const float4*>(gumbel + (size_t)(n0 + l15) * KK + pg0);

        f32x4 acc = {0.f, 0.f, 0.f, 0.f};
        if (PRE) {
            const uint4* afp = pb + (size_t)(c * CHUNK + pr) * 32;
#pragma unroll
            for (int ks = 0; ks < 8; ++ks) {
                int gi = ks * 4 + l4;
                bf16x8 af = __builtin_bit_cast(bf16x8, afp[gi]);
                bf16x8 b0 = *reinterpret_cast<bf16x8*>(
                    sm + LXS + l15 * 512 + ((gi ^ (l15 & 7)) << 4));
                acc = __builtin_amdgcn_mfma_f32_16x16x32_bf16(af, b0, acc, 0, 0, 0);
            }
        } else {
#pragma unroll
            for (int ks = 0; ks < 8; ++ks) {
                int gi = ks * 4 + l4;
                bf16x8 af = *reinterpret_cast<bf16x8*>(
                    sm + LPS + pr * 512 + ((gi ^ (pr & 7)) << 4));
                bf16x8 b0 = *reinterpret_cast<bf16x8*>(
                    sm + LXS + l15 * 512 + ((gi ^ (l15 & 7)) << 4));
                acc = __builtin_amdgcn_mfma_f32_16x16x32_bf16(af, b0, acc, 0, 0, 0);
            }
        }
        // ---- epilogue: S = 2*acc - np2 + gumbel -> bf16 Ss (swizzled b64 write) ----
        {
            const int Gs = pg0 >> 2;      // 8B-granule index within row
            uint2 pk;
            pk.x = pkbf2(fmaf(2.f, acc.x, -q4.x) + g4.x, fmaf(2.f, acc.y, -q4.y) + g4.y);
            pk.y = pkbf2(fmaf(2.f, acc.z, -q4.z) + g4.z, fmaf(2.f, acc.w, -q4.w) + g4.w);
            *reinterpret_cast<uint2*>(sm + LSS + l15 * 2048 + ((Gs ^ ((l15 & 7) << 1)) << 3)) = pk;
        }
    }
    __syncthreads();

    // ---- Phase B: per-row max/argmax/logZ (32 threads per row) ----
    {
        int row = t >> 5, v = t & 31;
        int sw = (row & 7) << 1;
        uint2 d[8];
#pragma unroll
        for (int j = 0; j < 8; ++j) {
            int G = v + 32 * j;
            d[j] = *reinterpret_cast<uint2*>(sm + LSS + row * 2048 + ((G ^ sw) << 3));
        }
        float m = -3.4e38f; int mi = 0;
#pragma unroll
        for (int j = 0; j < 8; ++j) {
            int c0 = (v + 32 * j) * 4;
            float f0 = ubf(d[j].x & 0xffffu), f1 = ubf(d[j].x >> 16);
            float f2 = ubf(d[j].y & 0xffffu), f3 = ubf(d[j].y >> 16);
            if (f0 > m) { m = f0; mi = c0; }
            if (f1 > m) { m = f1; mi = c0 + 1; }
            if (f2 > m) { m = f2; mi = c0 + 2; }
            if (f3 > m) { m = f3; mi = c0 + 3; }
        }
#pragma unroll
        for (int off = 1; off < 32; off <<= 1) {
            float om = __shfl_xor(m, off);
            int oi = __shfl_xor(mi, off);
            if (om > m || (om == m && oi < mi)) { m = om; mi = oi; }
        }
        float se = 0.f;
#pragma unroll
        for (int j = 0; j < 8; ++j) {
            se += __expf(ubf(d[j].x & 0xffffu) - m);
            se += __expf(ubf(d[j].x >> 16) - m);
            se += __expf(ubf(d[j].y & 0xffffu) - m);
            se += __expf(ubf(d[j].y >> 16) - m);
        }
#pragma unroll
        for (int off = 1; off < 32; off <<= 1) se += __shfl_xor(se, off);
        if (v == 0) {
            *reinterpret_cast<float*>(sm + LRM + row * 4) = m + __logf(se);
            *reinterpret_cast<int*>(sm + LRI + row * 4) = mi;
        }
    }
    __syncthreads();

    // ---- Phase C1: column partial sums -> global atomics (2 cols/thread) ----
#pragma unroll
    for (int h = 0; h < 2; ++h) {
        int col = t + h * NTHR;
        int G = col >> 2;
        int e2 = (col & 3) << 1;
        float sy = 0.f, slp = 0.f;
#pragma unroll 8
        for (int r = 0; r < BM; ++r) {
            uint32_t hv = *reinterpret_cast<uint16_t*>(
                sm + LSS + r * 2048 + ((G ^ ((r & 7) << 1)) << 3) + e2);
            float lz = *reinterpret_cast<float*>(sm + LRM + r * 4);
            float lp = ubf(hv) - lz;
            slp += lp;
            sy += __expf(lp);
        }
        atomicAdd(&colsum_y[col], sy);
        atomicAdd(&colsum_lp[col], slp);
    }

    // ---- Phase C2: quantized = protos[argmax] (f32 gather), 32 thr/row ----
    {
        int row = t >> 5, v = t & 31;
        int idx = *reinterpret_cast<int*>(sm + LRI + row * 4);
        const float4* src = reinterpret_cast<const float4*>(protos + (size_t)idx * DD + v * 8);
        float4* dst = reinterpret_cast<float4*>(out + (size_t)(n0 + row) * DD + v * 8);
        dst[0] = src[0];
        dst[1] = src[1];
    }
}

__global__ void vq_final(const float* __restrict__ ws,
                         float* __restrict__ out, int out_size) {
    __shared__ float part[4];
    int t = threadIdx.x;  // 1 block x 256
    const float invN = 1.0f / (float)NN;
    float a = 0.f;
    for (int j = 0; j < 4; ++j) {
        int k = t + j * 256;
        float prior = fmaf(ws[KK + k], invN, 1e-6f);
        float Lk = ws[2 * KK + k] * invN;
        a += prior * (1.001f * __logf(prior) - Lk);
    }
#pragma unroll
    for (int off = 32; off >= 1; off >>= 1) a += __shfl_xor(a, off);
    if ((t & 63) == 0) part[t >> 6] = a;
    __syncthreads();
    if (t == 0) {
        out[out_size - 1] = part[0] + part[1] + part[2] + part[3];
    }
}

extern "C" void kernel_launch(void* const* d_in, const int* in_sizes, int n_in,
                              void* d_out, int out_size, void* d_ws, size_t ws_size,
                              hipStream_t stream) {
    (void)in_sizes; (void)n_in;
    const float* latents = (const float*)d_in[0];
    const float* protos  = (const float*)d_in[1];
    const float* gumbel  = (const float*)d_in[2];
    float* out           = (float*)d_out;
    float* ws            = (float*)d_ws;

    bool pre = ws_size >= (size_t)(3 * KK * 4 + KK * DD * 2);

    vq_init<<<dim3(4), dim3(256), 0, stream>>>(protos, ws);
    if (pre) {
        vq_cvt<<<dim3(KK * DD / 2048), dim3(256), 0, stream>>>(
            protos, (uint32_t*)(ws + 3 * KK));
        vq_mainT<true><<<dim3(NN / BM), dim3(NTHR), 0, stream>>>(
            latents, protos, gumbel, ws, out);
    } else {
        vq_mainT<false><<<dim3(NN / BM), dim3(NTHR), 0, stream>>>(
            latents, protos, gumbel, ws, out);
    }
    vq_final<<<dim3(1), dim3(256), 0, stream>>>(ws, out, out_size);
}

// Round 10
// 119.808 us; speedup vs baseline: 2.4315x; 1.3685x over previous
//
#include <hip/hip_runtime.h>
#include <hip/hip_bf16.h>
#include <stdint.h>

#define NN 32768
#define KK 1024
#define DD 256
#define BM 16
#define CHUNK 128
#define NCHUNK (KK / CHUNK)   // 8
#define NTHR 512
#define NRB (NN / BM)         // 2048 row-blocks

// ---- kernel A LDS: Xs 8KB | Ps 64KB | scratch ----
#define LXS 0
#define LPS 8192
#define ASC_MAXP 73728   // [16 rows][8 waves] {f32 m, i32 mi} = 1024B
#define ASC_ZP   74752   // [16][8] f32 = 512B
#define ASC_MI   75264   // [16] i32
#define LA_TOT   75328

// ---- round-9 fallback LDS ----
#define LSS 8192
#define LRM (LSS + 32768)
#define LRI (LRM + 64)
#define FLPS 41216
#define LTOT_PRE  41216
#define LTOT_NPRE (41216 + 65536)

// ws layout (bytes):
// [0, 4096)        np2 f32[1024]
// [4096, 8192)     colsum_y f32[1024]
// [8192, 12288)    colsum_lp f32[1024]
// [12288, 536576)  pb: bf16 protos, uint4-granules
// [536576, +64MB)  Sbuf uint2[NRB*8*512]   (full path only)
// [67645440, +128KB) lzbuf f32[NN]
#define PB_OFF   12288
#define SBUF_OFF 536576
#define LZ_OFF   (SBUF_OFF + (size_t)NRB * NCHUNK * 512 * 8)   // 67645440
#define WS_FULL  (LZ_OFF + (size_t)NN * 4)
#define WS_PRE   (PB_OFF + (size_t)KK * DD * 2)

typedef __attribute__((ext_vector_type(8))) short bf16x8;
typedef __attribute__((ext_vector_type(4))) float f32x4;

__device__ __forceinline__ uint32_t pkbf2(float a, float b) {  // RNE f32->bf16 pack
    uint32_t ua = __builtin_bit_cast(uint32_t, a);
    uint32_t ub = __builtin_bit_cast(uint32_t, b);
    ua = (ua + 0x7fffu + ((ua >> 16) & 1u)) >> 16;
    ub = (ub + 0x7fffu + ((ub >> 16) & 1u)) >> 16;
    return ua | (ub << 16);
}
__device__ __forceinline__ float ubf(uint32_t h) {
    return __builtin_bit_cast(float, h << 16);
}

__global__ void vq_init(const float* __restrict__ protos, float* __restrict__ ws) {
    int k = blockIdx.x * 256 + threadIdx.x;   // grid 4 x 256
    const float4* p4 = reinterpret_cast<const float4*>(protos + (size_t)k * DD);
    float s = 0.f;
#pragma unroll 8
    for (int j = 0; j < DD / 4; ++j) {
        float4 v = p4[j];
        s = fmaf(v.x, v.x, s); s = fmaf(v.y, v.y, s);
        s = fmaf(v.z, v.z, s); s = fmaf(v.w, v.w, s);
    }
    ws[k] = s;
    ws[KK + k] = 0.f;
    ws[2 * KK + k] = 0.f;
}

__global__ void vq_cvt(const float* __restrict__ protos, uint32_t* __restrict__ pb) {
    int idx = blockIdx.x * 256 + threadIdx.x;  // 0..32767
    const float4* s = reinterpret_cast<const float4*>(protos + (size_t)idx * 8);
    float4 a = s[0], b = s[1];
    uint4 v;
    v.x = pkbf2(a.x, a.y); v.y = pkbf2(a.z, a.w);
    v.z = pkbf2(b.x, b.y); v.w = pkbf2(b.z, b.w);
    reinterpret_cast<uint4*>(pb)[idx] = v;
}

// ================= kernel A: MFMA + online row stats + S -> global =========
__global__ __launch_bounds__(NTHR) void vq_mainA(const float* __restrict__ latents,
                                                 const float* __restrict__ protos,
                                                 const float* __restrict__ gumbel,
                                                 float* __restrict__ ws,
                                                 float* __restrict__ out) {
    __shared__ __align__(16) unsigned char sm[LA_TOT];
    const int t = threadIdx.x;
    const int lane = t & 63;
    const int w = t >> 6;
    const int rb = blockIdx.x;
    const int n0 = rb * BM;
    const int l15 = lane & 15;
    const int l4 = lane >> 4;
    const float* np2 = ws;
    const uint4* pb = reinterpret_cast<const uint4*>((char*)ws + PB_OFF);
    uint2* Sb = reinterpret_cast<uint2*>((char*)ws + SBUF_OFF);
    float* lzb = reinterpret_cast<float*>((char*)ws + LZ_OFF);

    // stage X: 16 rows x 256 f32 -> bf16 LDS (swizzled)
    {
        int row = t >> 5, g = t & 31;
        const float4* src = reinterpret_cast<const float4*>(
            latents + (size_t)(n0 + row) * DD + g * 8);
        float4 a = src[0], b = src[1];
        uint4 v; v.x = pkbf2(a.x, a.y); v.y = pkbf2(a.z, a.w);
        v.z = pkbf2(b.x, b.y); v.w = pkbf2(b.z, b.w);
        *reinterpret_cast<uint4*>(sm + LXS + row * 512 + ((g ^ (row & 7)) << 4)) = v;
    }

    const int pr = w * 16 + l15;
    const int cwbase = w * 16 + l4 * 4;
    float z = 0.f, m = -3.4e38f; int mi = 0;

    for (int c = 0; c < NCHUNK; ++c) {
        __syncthreads();          // Ps readers of prev chunk done (covers Xs 1st iter)
#pragma unroll
        for (int i = 0; i < 8; ++i) {
            int G = t + NTHR * i;
            int p = G >> 5, g = G & 31;
            *reinterpret_cast<uint4*>(sm + LPS + p * 512 + ((g ^ (p & 7)) << 4)) =
                pb[(size_t)(c * CHUNK + p) * 32 + g];
        }
        __syncthreads();

        const int pg0 = c * CHUNK + cwbase;
        float4 q4 = *reinterpret_cast<const float4*>(np2 + pg0);
        float4 g4 = *reinterpret_cast<const float4*>(gumbel + (size_t)(n0 + l15) * KK + pg0);

        f32x4 acc = {0.f, 0.f, 0.f, 0.f};
#pragma unroll
        for (int ks = 0; ks < 8; ++ks) {
            int gi = ks * 4 + l4;
            bf16x8 af = *reinterpret_cast<bf16x8*>(sm + LPS + pr * 512 + ((gi ^ (pr & 7)) << 4));
            bf16x8 b0 = *reinterpret_cast<bf16x8*>(sm + LXS + l15 * 512 + ((gi ^ (l15 & 7)) << 4));
            acc = __builtin_amdgcn_mfma_f32_16x16x32_bf16(af, b0, acc, 0, 0, 0);
        }
        float s0 = fmaf(2.f, acc.x, -q4.x) + g4.x;
        float s1 = fmaf(2.f, acc.y, -q4.y) + g4.y;
        float s2 = fmaf(2.f, acc.z, -q4.z) + g4.z;
        float s3 = fmaf(2.f, acc.w, -q4.w) + g4.w;
        z += __expf(s0) + __expf(s1) + __expf(s2) + __expf(s3);
        if (s0 > m) { m = s0; mi = pg0; }
        if (s1 > m) { m = s1; mi = pg0 + 1; }
        if (s2 > m) { m = s2; mi = pg0 + 2; }
        if (s3 > m) { m = s3; mi = pg0 + 3; }
        uint2 pk;
        pk.x = pkbf2(s0, s1);
        pk.y = pkbf2(s2, s3);
        Sb[((size_t)rb * NCHUNK + c) * 512 + t] = pk;   // 512B contiguous per wave
    }

    // row stats: reduce over l4 (lane bits 4,5)
#pragma unroll
    for (int off = 16; off <= 32; off <<= 1) {
        float om = __shfl_xor(m, off); int oi = __shfl_xor(mi, off);
        if (om > m || (om == m && oi < mi)) { m = om; mi = oi; }
        z += __shfl_xor(z, off);
    }
    if (lane < 16) {
        *reinterpret_cast<float*>(sm + ASC_MAXP + (l15 * 8 + w) * 8) = m;
        *reinterpret_cast<int*>(sm + ASC_MAXP + (l15 * 8 + w) * 8 + 4) = mi;
        *reinterpret_cast<float*>(sm + ASC_ZP + (l15 * 8 + w) * 4) = z;
    }
    __syncthreads();
    if (t < 16) {
        float mm = -3.4e38f; int mmi = 0; float Z = 0.f;
#pragma unroll
        for (int j = 0; j < 8; ++j) {
            float om = *reinterpret_cast<float*>(sm + ASC_MAXP + (t * 8 + j) * 8);
            int oi = *reinterpret_cast<int*>(sm + ASC_MAXP + (t * 8 + j) * 8 + 4);
            if (om > mm || (om == mm && oi < mmi)) { mm = om; mmi = oi; }
            Z += *reinterpret_cast<float*>(sm + ASC_ZP + (t * 8 + j) * 4);
        }
        lzb[n0 + t] = __logf(Z);
        *reinterpret_cast<int*>(sm + ASC_MI + t * 4) = mmi;
    }
    __syncthreads();

    // quantized = protos[argmax], 32 thr/row
    {
        int row = t >> 5, v = t & 31;
        int idx = *reinterpret_cast<int*>(sm + ASC_MI + row * 4);
        const float4* src = reinterpret_cast<const float4*>(protos + (size_t)idx * DD + v * 8);
        float4* dst = reinterpret_cast<float4*>(out + (size_t)(n0 + row) * DD + v * 8);
        dst[0] = src[0];
        dst[1] = src[1];
    }
}

// ================= kernel B: column sums from Sbuf ==========================
__global__ __launch_bounds__(NTHR) void vq_colsum(float* __restrict__ ws) {
    const int t = threadIdx.x;
    const int l15 = t & 15;
    const int c = blockIdx.x & 7;          // chunk
    const int rg = blockIdx.x >> 3;        // row-group: 64 row-blocks
    const uint2* Sb = reinterpret_cast<const uint2*>((char*)ws + SBUF_OFF);
    const float* lzb = reinterpret_cast<const float*>((char*)ws + LZ_OFF);
    float* colsum_y = ws + KK;
    float* colsum_lp = ws + 2 * KK;

    float sy0 = 0.f, sy1 = 0.f, sy2 = 0.f, sy3 = 0.f;
    float sl0 = 0.f, sl1 = 0.f, sl2 = 0.f, sl3 = 0.f;
    for (int i = 0; i < NRB / 32; ++i) {   // 64 row-blocks
        int rb = rg * (NRB / 32) + i;
        uint2 v = Sb[((size_t)rb * NCHUNK + c) * 512 + t];
        float lz = lzb[rb * BM + l15];
        float a0 = ubf(v.x & 0xffffu) - lz, a1 = ubf(v.x >> 16) - lz;
        float a2 = ubf(v.y & 0xffffu) - lz, a3 = ubf(v.y >> 16) - lz;
        sy0 += __expf(a0); sy1 += __expf(a1); sy2 += __expf(a2); sy3 += __expf(a3);
        sl0 += a0; sl1 += a1; sl2 += a2; sl3 += a3;
    }
#pragma unroll
    for (int off = 1; off < 16; off <<= 1) {
        sy0 += __shfl_xor(sy0, off); sy1 += __shfl_xor(sy1, off);
        sy2 += __shfl_xor(sy2, off); sy3 += __shfl_xor(sy3, off);
        sl0 += __shfl_xor(sl0, off); sl1 += __shfl_xor(sl1, off);
        sl2 += __shfl_xor(sl2, off); sl3 += __shfl_xor(sl3, off);
    }
    if (l15 == 0) {
        int w = t >> 6, l4 = (t & 63) >> 4;
        int cb = c * CHUNK + w * 16 + l4 * 4;
        atomicAdd(&colsum_y[cb],     sy0); atomicAdd(&colsum_y[cb + 1], sy1);
        atomicAdd(&colsum_y[cb + 2], sy2); atomicAdd(&colsum_y[cb + 3], sy3);
        atomicAdd(&colsum_lp[cb],     sl0); atomicAdd(&colsum_lp[cb + 1], sl1);
        atomicAdd(&colsum_lp[cb + 2], sl2); atomicAdd(&colsum_lp[cb + 3], sl3);
    }
}

// ================= round-9 fallback main kernel =============================
template<bool PRE>
__global__ __launch_bounds__(NTHR) void vq_mainT(const float* __restrict__ latents,
                                                 const float* __restrict__ protos,
                                                 const float* __restrict__ gumbel,
                                                 float* __restrict__ ws,
                                                 float* __restrict__ out) {
    __shared__ __align__(16) unsigned char sm[PRE ? LTOT_PRE : LTOT_NPRE];
    const int t = threadIdx.x;
    const int lane = t & 63;
    const int w = t >> 6;
    const int n0 = blockIdx.x * BM;
    const int l15 = lane & 15;
    const int l4 = lane >> 4;
    const float* np2 = ws;
    float* colsum_y = ws + KK;
    float* colsum_lp = ws + 2 * KK;
    const uint4* pb = reinterpret_cast<const uint4*>((char*)ws + PB_OFF);

    {
        int row = t >> 5, g = t & 31;
        const float4* src = reinterpret_cast<const float4*>(
            latents + (size_t)(n0 + row) * DD + g * 8);
        float4 a = src[0], b = src[1];
        uint4 v; v.x = pkbf2(a.x, a.y); v.y = pkbf2(a.z, a.w);
        v.z = pkbf2(b.x, b.y); v.w = pkbf2(b.z, b.w);
        *reinterpret_cast<uint4*>(sm + LXS + row * 512 + ((g ^ (row & 7)) << 4)) = v;
    }
    __syncthreads();

    const int pr = w * 16 + l15;
    const int cwbase = w * 16 + l4 * 4;

    for (int c = 0; c < NCHUNK; ++c) {
        if (!PRE) {
            __syncthreads();
#pragma unroll
            for (int i = 0; i < 8; ++i) {
                int G = t + NTHR * i;
                int p = G >> 5, g = G & 31;
                const float4* src = reinterpret_cast<const float4*>(
                    protos + (size_t)(c * CHUNK + p) * DD + g * 8);
                float4 a = src[0], b = src[1];
                uint4 v; v.x = pkbf2(a.x, a.y); v.y = pkbf2(a.z, a.w);
                v.z = pkbf2(b.x, b.y); v.w = pkbf2(b.z, b.w);
                *reinterpret_cast<uint4*>(sm + FLPS + p * 512 + ((g ^ (p & 7)) << 4)) = v;
            }
            __syncthreads();
        }
        const int pg0 = c * CHUNK + cwbase;
        float4 q4 = *reinterpret_cast<const float4*>(np2 + pg0);
        float4 g4 = *reinterpret_cast<const float4*>(gumbel + (size_t)(n0 + l15) * KK + pg0);

        f32x4 acc = {0.f, 0.f, 0.f, 0.f};
        if (PRE) {
            const uint4* afp = pb + (size_t)(c * CHUNK + pr) * 32;
#pragma unroll
            for (int ks = 0; ks < 8; ++ks) {
                int gi = ks * 4 + l4;
                bf16x8 af = __builtin_bit_cast(bf16x8, afp[gi]);
                bf16x8 b0 = *reinterpret_cast<bf16x8*>(
                    sm + LXS + l15 * 512 + ((gi ^ (l15 & 7)) << 4));
                acc = __builtin_amdgcn_mfma_f32_16x16x32_bf16(af, b0, acc, 0, 0, 0);
            }
        } else {
#pragma unroll
            for (int ks = 0; ks < 8; ++ks) {
                int gi = ks * 4 + l4;
                bf16x8 af = *reinterpret_cast<bf16x8*>(
                    sm + FLPS + pr * 512 + ((gi ^ (pr & 7)) << 4));
                bf16x8 b0 = *reinterpret_cast<bf16x8*>(
                    sm + LXS + l15 * 512 + ((gi ^ (l15 & 7)) << 4));
                acc = __builtin_amdgcn_mfma_f32_16x16x32_bf16(af, b0, acc, 0, 0, 0);
            }
        }
        {
            const int Gs = pg0 >> 2;
            uint2 pk;
            pk.x = pkbf2(fmaf(2.f, acc.x, -q4.x) + g4.x, fmaf(2.f, acc.y, -q4.y) + g4.y);
            pk.y = pkbf2(fmaf(2.f, acc.z, -q4.z) + g4.z, fmaf(2.f, acc.w, -q4.w) + g4.w);
            *reinterpret_cast<uint2*>(sm + LSS + l15 * 2048 + ((Gs ^ ((l15 & 7) << 1)) << 3)) = pk;
        }
    }
    __syncthreads();

    {
        int row = t >> 5, v = t & 31;
        int sw = (row & 7) << 1;
        uint2 d[8];
#pragma unroll
        for (int j = 0; j < 8; ++j) {
            int G = v + 32 * j;
            d[j] = *reinterpret_cast<uint2*>(sm + LSS + row * 2048 + ((G ^ sw) << 3));
        }
        float m = -3.4e38f; int mi = 0;
#pragma unroll
        for (int j = 0; j < 8; ++j) {
            int c0 = (v + 32 * j) * 4;
            float f0 = ubf(d[j].x & 0xffffu), f1 = ubf(d[j].x >> 16);
            float f2 = ubf(d[j].y & 0xffffu), f3 = ubf(d[j].y >> 16);
            if (f0 > m) { m = f0; mi = c0; }
            if (f1 > m) { m = f1; mi = c0 + 1; }
            if (f2 > m) { m = f2; mi = c0 + 2; }
            if (f3 > m) { m = f3; mi = c0 + 3; }
        }
#pragma unroll
        for (int off = 1; off < 32; off <<= 1) {
            float om = __shfl_xor(m, off);
            int oi = __shfl_xor(mi, off);
            if (om > m || (om == m && oi < mi)) { m = om; mi = oi; }
        }
        float se = 0.f;
#pragma unroll
        for (int j = 0; j < 8; ++j) {
            se += __expf(ubf(d[j].x & 0xffffu) - m);
            se += __expf(ubf(d[j].x >> 16) - m);
            se += __expf(ubf(d[j].y & 0xffffu) - m);
            se += __expf(ubf(d[j].y >> 16) - m);
        }
#pragma unroll
        for (int off = 1; off < 32; off <<= 1) se += __shfl_xor(se, off);
        if (v == 0) {
            *reinterpret_cast<float*>(sm + LRM + row * 4) = m + __logf(se);
            *reinterpret_cast<int*>(sm + LRI + row * 4) = mi;
        }
    }
    __syncthreads();

#pragma unroll
    for (int h = 0; h < 2; ++h) {
        int col = t + h * NTHR;
        int G = col >> 2;
        int e2 = (col & 3) << 1;
        float sy = 0.f, slp = 0.f;
#pragma unroll 8
        for (int r = 0; r < BM; ++r) {
            uint32_t hv = *reinterpret_cast<uint16_t*>(
                sm + LSS + r * 2048 + ((G ^ ((r & 7) << 1)) << 3) + e2);
            float lz = *reinterpret_cast<float*>(sm + LRM + r * 4);
            float lp = ubf(hv) - lz;
            slp += lp;
            sy += __expf(lp);
        }
        atomicAdd(&colsum_y[col], sy);
        atomicAdd(&colsum_lp[col], slp);
    }

    {
        int row = t >> 5, v = t & 31;
        int idx = *reinterpret_cast<int*>(sm + LRI + row * 4);
        const float4* src = reinterpret_cast<const float4*>(protos + (size_t)idx * DD + v * 8);
        float4* dst = reinterpret_cast<float4*>(out + (size_t)(n0 + row) * DD + v * 8);
        dst[0] = src[0];
        dst[1] = src[1];
    }
}

__global__ void vq_final(const float* __restrict__ ws,
                         float* __restrict__ out, int out_size) {
    __shared__ float part[4];
    int t = threadIdx.x;  // 1 block x 256
    const float invN = 1.0f / (float)NN;
    float a = 0.f;
    for (int j = 0; j < 4; ++j) {
        int k = t + j * 256;
        float prior = fmaf(ws[KK + k], invN, 1e-6f);
        float Lk = ws[2 * KK + k] * invN;
        a += prior * (1.001f * __logf(prior) - Lk);
    }
#pragma unroll
    for (int off = 32; off >= 1; off >>= 1) a += __shfl_xor(a, off);
    if ((t & 63) == 0) part[t >> 6] = a;
    __syncthreads();
    if (t == 0) {
        out[out_size - 1] = part[0] + part[1] + part[2] + part[3];
    }
}

extern "C" void kernel_launch(void* const* d_in, const int* in_sizes, int n_in,
                              void* d_out, int out_size, void* d_ws, size_t ws_size,
                              hipStream_t stream) {
    (void)in_sizes; (void)n_in;
    const float* latents = (const float*)d_in[0];
    const float* protos  = (const float*)d_in[1];
    const float* gumbel  = (const float*)d_in[2];
    float* out           = (float*)d_out;
    float* ws            = (float*)d_ws;

    vq_init<<<dim3(4), dim3(256), 0, stream>>>(protos, ws);
    if (ws_size >= WS_FULL) {
        vq_cvt<<<dim3(KK * DD / 2048), dim3(256), 0, stream>>>(
            protos, (uint32_t*)((char*)d_ws + PB_OFF));
        vq_mainA<<<dim3(NRB), dim3(NTHR), 0, stream>>>(
            latents, protos, gumbel, ws, out);
        vq_colsum<<<dim3(NCHUNK * 32), dim3(NTHR), 0, stream>>>(ws);
    } else if (ws_size >= WS_PRE) {
        vq_cvt<<<dim3(KK * DD / 2048), dim3(256), 0, stream>>>(
            protos, (uint32_t*)((char*)d_ws + PB_OFF));
        vq_mainT<true><<<dim3(NRB), dim3(NTHR), 0, stream>>>(
            latents, protos, gumbel, ws, out);
    } else {
        vq_mainT<false><<<dim3(NRB), dim3(NTHR), 0, stream>>>(
            latents, protos, gumbel, ws, out);
    }
    vq_final<<<dim3(1), dim3(256), 0, stream>>>(ws, out, out_size);
}